// Round 10
// baseline (214.292 us; speedup 1.0000x reference)
//
#include <hip/hip_runtime.h>
#include <stdint.h>

#define T_SEQ 2048
#define D_MODEL 1024
#define NH 16
#define DH 64
#define NROWS 4096  // B*T

typedef __bf16 bf16x8 __attribute__((ext_vector_type(8)));
typedef float floatx4 __attribute__((ext_vector_type(4)));

#define AS1 __attribute__((address_space(1)))
#define AS3 __attribute__((address_space(3)))

static __device__ __forceinline__ void gl2lds16(const unsigned short* g, unsigned short* s) {
    __builtin_amdgcn_global_load_lds((const AS1 unsigned int*)g, (AS3 unsigned int*)s, 16, 0, 0);
}

static __device__ __forceinline__ unsigned short f32_bf16(float f) {
    union { float f; unsigned int u; } c; c.f = f;
    unsigned int u = c.u;
    u = u + 0x7FFFu + ((u >> 16) & 1u);   // RNE
    return (unsigned short)(u >> 16);
}

static __device__ __forceinline__ unsigned int pack2_bf16(float a, float b) {
    return (unsigned int)f32_bf16(a) | ((unsigned int)f32_bf16(b) << 16);
}

static __device__ __forceinline__ floatx4 mfma16(bf16x8 a, bf16x8 b, floatx4 c) {
    return __builtin_amdgcn_mfma_f32_16x16x32_bf16(a, b, c, 0, 0, 0);
}

#define QSCALE 0.1803368801111204f   // (1/8) * log2(e); softmax in exp2 domain
#define EXP2_SHIFT 10.0f
// s_waitcnt imm: vmcnt[3:0], expcnt[6:4]=7 (nowait), lgkmcnt[11:8]=0xF (nowait)
#define WAITCNT_VM(n) (0x0F70 | (n))

// ---------------- fused conversion kernel ----------------
__global__ __launch_bounds__(256) void k_conv_all(const float* __restrict__ x,
                                                  const float* __restrict__ Wq,
                                                  const float* __restrict__ Wk,
                                                  const float* __restrict__ Wv,
                                                  const float* __restrict__ Wo,
                                                  unsigned short* __restrict__ x_bf,
                                                  unsigned short* __restrict__ wqkv_bf,
                                                  unsigned short* __restrict__ wo_bf) {
    int b = blockIdx.x, t = threadIdx.x;
    if (b < 4096) {
        int i = b * 1024 + t * 4;
        float4 v = *(const float4*)(x + i);
        uint2 o;
        o.x = pack2_bf16(v.x, v.y);
        o.y = pack2_bf16(v.z, v.w);
        *(uint2*)(x_bf + i) = o;
    } else if (b < 7168) {
        int idx = b - 4096;
        int tensor = idx >> 10, np = idx & 1023;
        const float* src = tensor == 0 ? Wq : tensor == 1 ? Wk : Wv;
        int f = (np & 63) * 16 + (np >> 6);
        int c = t * 4;
        float4 v = *(const float4*)(src + (long)f * D_MODEL + c);
        uint2 o;
        o.x = pack2_bf16(v.x, v.y);
        o.y = pack2_bf16(v.z, v.w);
        *(uint2*)(wqkv_bf + ((long)tensor * D_MODEL + np) * D_MODEL + c) = o;
    } else {
        int n = b - 7168;
        int fp = t * 4;
        const float* row = Wo + (long)n * D_MODEL;
        unsigned short o[4];
        #pragma unroll
        for (int k = 0; k < 4; k++) {
            int f = fp + k;
            o[k] = f32_bf16(row[(f & 63) * 16 + (f >> 6)]);
        }
        *(uint2*)(wo_bf + (long)n * D_MODEL + fp) = *(const uint2*)o;
    }
}

// ---------------- GEMM: C = A(bf16) @ W(bf16)^T, K = 1024 ----------------
// Double-buffered LDS K-loop; raw s_barrier + manual partial vmcnt.
// MODE 0: fused QKV (W stacked 3072x1024); grid 768. V -> plain V^T[bh][d][j].
// MODE 1: O-proj; grid 512.
template <int BN, int MODE>
__global__ __launch_bounds__(256) void k_gemm(const unsigned short* __restrict__ A,
                                              const unsigned short* __restrict__ W,
                                              const float* __restrict__ b0,
                                              const float* __restrict__ b1,
                                              const float* __restrict__ b2,
                                              const float* __restrict__ resid,
                                              unsigned short* __restrict__ out_bf,
                                              unsigned short* __restrict__ vt,
                                              float* __restrict__ out_f32) {
    constexpr int NT = BN / 32;
    constexpr int NCB = BN / 32;
    constexpr int NDMA = 4 + NCB;            // DMA instrs per thread per stage
    __shared__ unsigned short lds_a[2 * 128 * 64];
    __shared__ unsigned short lds_b[2 * BN * 64];
    const int tid = threadIdx.x;
    const int w = tid >> 6, l = tid & 63;
    const int lrow = l & 15, lq = l >> 4;
    const int wm = (w >> 1) * 64, wn = (w & 1) * (BN / 2);
    const int L = blockIdx.x;
    const int bx = (L & 7) * 4 + ((L >> 3) & 3);
    const int by = L >> 5;
    const long am0 = (long)bx * 128;
    const long wn0 = (long)by * BN;

    floatx4 acc[4][NT] = {};
    const int grow = l >> 3;
    const int gcol = ((l & 7) ^ grow) * 8;   // column-group XOR swizzle (global side)
    const int sw8 = (lrow & 7);

    auto stage = [&](int ki, int sel) {
        unsigned short* la = lds_a + sel * 8192;
        unsigned short* lb = lds_b + sel * (BN * 64);
        int k0 = ki * 64;
        #pragma unroll
        for (int c = 0; c < 4; c++) {
            int chunk = w * 4 + c;
            gl2lds16(A + (am0 + chunk * 8 + grow) * D_MODEL + k0 + gcol, la + chunk * 512);
        }
        #pragma unroll
        for (int c = 0; c < NCB; c++) {
            int chunk = w * NCB + c;
            gl2lds16(W + (wn0 + chunk * 8 + grow) * D_MODEL + k0 + gcol, lb + chunk * 512);
        }
    };

    stage(0, 0);

    for (int i = 0; i < 16; i++) {
        const int cur = i & 1;
        if (i < 15) {
            stage(i + 1, 1 - cur);
            __builtin_amdgcn_s_waitcnt(WAITCNT_VM(NDMA));  // drain stage(i), keep stage(i+1)
        } else {
            __builtin_amdgcn_s_waitcnt(WAITCNT_VM(0));
        }
        __builtin_amdgcn_s_barrier();

        const unsigned short* la = lds_a + cur * 8192;
        const unsigned short* lb = lds_b + cur * (BN * 64);
        bf16x8 af[4][2], bf[NT][2];
        #pragma unroll
        for (int mt = 0; mt < 4; mt++)
            #pragma unroll
            for (int ks = 0; ks < 2; ks++)
                af[mt][ks] = *(const bf16x8*)(la + (wm + mt * 16 + lrow) * 64 +
                                              (((ks * 4 + lq) ^ sw8) * 8));
        #pragma unroll
        for (int nt = 0; nt < NT; nt++)
            #pragma unroll
            for (int ks = 0; ks < 2; ks++)
                bf[nt][ks] = *(const bf16x8*)(lb + (wn + nt * 16 + lrow) * 64 +
                                              (((ks * 4 + lq) ^ sw8) * 8));
        #pragma unroll
        for (int mt = 0; mt < 4; mt++)
            #pragma unroll
            for (int nt = 0; nt < NT; nt++)
                #pragma unroll
                for (int ks = 0; ks < 2; ks++)
                    acc[mt][nt] = mfma16(af[mt][ks], bf[nt][ks], acc[mt][nt]);
        __builtin_amdgcn_s_barrier();   // raw: reads of buf[cur] done before restage (i+2)
    }

    if (MODE == 0) {
        int tensor = by >> 3;                    // 0=Q 1=K 2=V
        int nbase = (by & 7) * 128;
        const float* bias = tensor == 0 ? b0 : tensor == 1 ? b1 : b2;
        float scale = tensor == 0 ? QSCALE : 1.0f;
        if (tensor < 2) {
            unsigned short* outt = out_bf + (size_t)tensor * (32u * T_SEQ * DH);
            #pragma unroll
            for (int mt = 0; mt < 4; mt++) {
                #pragma unroll
                for (int nt = 0; nt < NT; nt++) {
                    int n = nbase + wn + nt * 16 + lrow;     // n' = h*64+d
                    int h = n >> 6, d = n & 63;
                    float bb = bias[d * 16 + h];
                    #pragma unroll
                    for (int r = 0; r < 4; r++) {
                        int row = (int)am0 + wm + mt * 16 + lq * 4 + r;
                        float v = (acc[mt][nt][r] + bb) * scale;
                        int b = row >> 11, i = row & 2047;
                        long idx = ((long)(b * 16 + h) * T_SEQ + i) * DH + d;
                        outt[idx] = f32_bf16(v);
                    }
                }
            }
        } else {
            // V^T: vt[(bh*64 + d)*T_SEQ + j], 4 consecutive j per b64 store
            int row0 = (int)am0 + wm;
            int b = row0 >> 11;
            int j0 = row0 & 2047;
            #pragma unroll
            for (int nt = 0; nt < NT; nt++) {
                int n = nbase + wn + nt * 16 + lrow;
                int h = n >> 6, d = n & 63;
                float bb = bias[d * 16 + h];
                long base = ((long)(b * 16 + h) * 64 + d) * T_SEQ;
                #pragma unroll
                for (int mt = 0; mt < 4; mt++) {
                    uint2 o;
                    o.x = pack2_bf16(acc[mt][nt][0] + bb, acc[mt][nt][1] + bb);
                    o.y = pack2_bf16(acc[mt][nt][2] + bb, acc[mt][nt][3] + bb);
                    *(uint2*)(vt + base + j0 + mt * 16 + lq * 4) = o;
                }
            }
        }
    } else {
        #pragma unroll
        for (int mt = 0; mt < 4; mt++) {
            #pragma unroll
            for (int nt = 0; nt < NT; nt++) {
                int n = (int)wn0 + wn + nt * 16 + lrow;
                float bb = b0[n];
                #pragma unroll
                for (int r = 0; r < 4; r++) {
                    int row = (int)am0 + wm + mt * 16 + lq * 4 + r;
                    long idx = (long)row * D_MODEL + n;
                    out_f32[idx] = acc[mt][nt][r] + bb + resid[idx];
                }
            }
        }
    }
}

// ---------------- attention: all-K32 MFMA; P via per-wave LDS roundtrip ----------
// S^T = mfma(A=K,B=Q) -> lane holds P^T[j=lq*4+r][i=lrow]. Write swizzled b64 to a
// per-wave pbuf in [i][j] layout, read back as the 16x16x32 B-fragment
// (P[i=lrow][j=h*32+lq*8..+7]); PV = mfma(A=V^T plain rows, B=P-frag);
// l = mfma(ones, P-frag). No K=16 MFMAs anywhere. DS ops are wave-in-order, so the
// pbuf needs no barriers. K/V double-buffered DMA with raw barriers (r9 structure).
__global__ __launch_bounds__(256) void k_attn(const unsigned short* __restrict__ q_ws,
                                              const unsigned short* __restrict__ k_ws,
                                              const unsigned short* __restrict__ vt,
                                              unsigned short* __restrict__ att) {
    __shared__ unsigned short kbuf[2 * 64 * 64];   // 16 KB
    __shared__ unsigned short vbuf[2 * 64 * 64];   // 16 KB
    __shared__ unsigned short pbuf[4][16 * 64];    // 8 KB, per-wave
    const int tid = threadIdx.x;
    const int w = tid >> 6, l = tid & 63;
    const int lrow = l & 15, lq = l >> 4;
    const int sw = lrow & 7;
    const int L = blockIdx.x;
    const int bh = (L & 7) * 4 + ((L >> 3) & 3);   // 4 bh per XCD -> K/V L2-resident
    const int i0 = (L >> 5) * 128;
    const unsigned short* kh = k_ws + (long)bh * T_SEQ * DH;
    const unsigned short* vh = vt + (long)bh * 64 * T_SEQ;   // plain V^T[d][j]

    const int rl = l >> 3;                     // staging: row within 8-row chunk
    const int gl = ((l & 7) ^ rl) * 8;         // staging: swizzled granule (shorts)

    bf16x8 qf[2][2];
    #pragma unroll
    for (int qt = 0; qt < 2; qt++) {
        const unsigned short* qp =
            q_ws + ((long)bh * T_SEQ + i0 + w * 32 + qt * 16 + lrow) * DH + lq * 8;
        qf[qt][0] = *(const bf16x8*)qp;
        qf[qt][1] = *(const bf16x8*)(qp + 32);
    }
    floatx4 o_acc[2][4] = {};
    floatx4 l_acc[2] = {};
    bf16x8 ones;
    {
        union { unsigned short s[8]; bf16x8 v; } cv;
        #pragma unroll
        for (int k = 0; k < 8; k++) cv.s[k] = 0x3F80;
        ones = cv.v;
    }

    // pbuf addressing (precomputed, shorts): row lrow (64 shorts), 16B granules XOR sw
    unsigned short* pw = &pbuf[w][0];
    int pwr[4], prd[2];
    #pragma unroll
    for (int nt = 0; nt < 4; nt++)
        pwr[nt] = lrow * 64 + (((nt * 2 + (lq >> 1)) ^ sw) * 8) + (lq & 1) * 4;
    #pragma unroll
    for (int h = 0; h < 2; h++)
        prd[h] = lrow * 64 + (((h * 4 + lq) ^ sw) * 8);

    auto stage = [&](int jt, int sel) {
        unsigned short* kd = kbuf + sel * 4096 + (w * 2) * 512;
        unsigned short* vd = vbuf + sel * 4096 + (w * 2) * 512;
        #pragma unroll
        for (int c = 0; c < 2; c++) {
            int row = w * 16 + c * 8 + rl;     // 0..63
            gl2lds16(kh + ((long)(jt * 64 + row)) * 64 + gl, kd + c * 512);
            gl2lds16(vh + (long)row * T_SEQ + jt * 64 + gl, vd + c * 512);
        }
    };

    stage(0, 0);

    constexpr int NTILE = T_SEQ / 64;
    for (int jt = 0; jt < NTILE; jt++) {
        const int cur = jt & 1;
        if (jt < NTILE - 1) {
            stage(jt + 1, 1 - cur);
            __builtin_amdgcn_s_waitcnt(WAITCNT_VM(4));   // drain tile jt, keep jt+1
        } else {
            __builtin_amdgcn_s_waitcnt(WAITCNT_VM(0));
        }
        __builtin_amdgcn_s_barrier();

        const unsigned short* kb_ = kbuf + cur * 4096;
        const unsigned short* vb_ = vbuf + cur * 4096;

        // K-frags (8 b128), then S^T - 10 for both q-tiles
        floatx4 s0[4], s1[4];
        #pragma unroll
        for (int nt = 0; nt < 4; nt++) {
            const unsigned short* kp = kb_ + (nt * 16 + lrow) * 64;
            bf16x8 ka = *(const bf16x8*)(kp + ((lq ^ sw) * 8));
            bf16x8 kb = *(const bf16x8*)(kp + (((lq + 4) ^ sw) * 8));
            floatx4 c0 = {-EXP2_SHIFT, -EXP2_SHIFT, -EXP2_SHIFT, -EXP2_SHIFT};
            floatx4 c1 = c0;
            c0 = mfma16(ka, qf[0][0], c0);
            c0 = mfma16(kb, qf[0][1], c0);
            c1 = mfma16(ka, qf[1][0], c1);
            c1 = mfma16(kb, qf[1][1], c1);
            s0[nt] = c0;
            s1[nt] = c1;
        }
        // V^T A-frags (8 b128), shared by both q-tiles
        bf16x8 vf[4][2];
        #pragma unroll
        for (int dt = 0; dt < 4; dt++) {
            const unsigned short* vp = vb_ + (dt * 16 + lrow) * 64;
            vf[dt][0] = *(const bf16x8*)(vp + ((lq ^ sw) * 8));
            vf[dt][1] = *(const bf16x8*)(vp + (((lq + 4) ^ sw) * 8));
        }
        // per q-tile: exp2 -> pack -> pbuf roundtrip -> l + PV (all K=32 MFMA)
        #pragma unroll
        for (int qt = 0; qt < 2; qt++) {
            const floatx4* s = (qt == 0) ? s0 : s1;
            #pragma unroll
            for (int nt = 0; nt < 4; nt++) {
                float p0 = __builtin_amdgcn_exp2f(s[nt][0]);
                float p1 = __builtin_amdgcn_exp2f(s[nt][1]);
                float p2 = __builtin_amdgcn_exp2f(s[nt][2]);
                float p3 = __builtin_amdgcn_exp2f(s[nt][3]);
                uint2 pk;
                pk.x = __builtin_amdgcn_perm(__float_as_uint(p1), __float_as_uint(p0), 0x07060302);
                pk.y = __builtin_amdgcn_perm(__float_as_uint(p3), __float_as_uint(p2), 0x07060302);
                *(uint2*)(pw + pwr[nt]) = pk;
            }
            bf16x8 pf0 = *(const bf16x8*)(pw + prd[0]);
            bf16x8 pf1 = *(const bf16x8*)(pw + prd[1]);
            l_acc[qt] = mfma16(ones, pf0, l_acc[qt]);
            l_acc[qt] = mfma16(ones, pf1, l_acc[qt]);
            #pragma unroll
            for (int dt = 0; dt < 4; dt++) {
                o_acc[qt][dt] = mfma16(vf[dt][0], pf0, o_acc[qt][dt]);
                o_acc[qt][dt] = mfma16(vf[dt][1], pf1, o_acc[qt][dt]);
            }
        }
        __builtin_amdgcn_s_barrier();   // raw: all reads of buf[cur] done before restage
    }
    int h = bh & 15, b = bh >> 4;
    #pragma unroll
    for (int qt = 0; qt < 2; qt++) {
        float rl2 = 1.0f / l_acc[qt][0];
        int i = i0 + w * 32 + qt * 16 + lrow;
        unsigned short* orow = att + ((long)(b * T_SEQ + i)) * D_MODEL + h * 64;
        #pragma unroll
        for (int dt = 0; dt < 4; dt++) {
            uint2 o;
            o.x = pack2_bf16(o_acc[qt][dt][0] * rl2, o_acc[qt][dt][1] * rl2);
            o.y = pack2_bf16(o_acc[qt][dt][2] * rl2, o_acc[qt][dt][3] * rl2);
            *(uint2*)(orow + dt * 16 + lq * 4) = o;
        }
    }
}

// ---------------- LayerNorm in-place on d_out ----------------
__global__ __launch_bounds__(256) void k_ln(float* __restrict__ io,
                                            const float* __restrict__ gamma,
                                            const float* __restrict__ beta) {
    int row = blockIdx.x, t = threadIdx.x;
    float* p = io + (long)row * D_MODEL + t * 4;
    float4 v = *(float4*)p;
    float s = v.x + v.y + v.z + v.w;
    float ss = v.x * v.x + v.y * v.y + v.z * v.z + v.w * v.w;
    #pragma unroll
    for (int m = 1; m < 64; m <<= 1) {
        s += __shfl_xor(s, m);
        ss += __shfl_xor(ss, m);
    }
    __shared__ float red[8];
    if ((t & 63) == 0) { red[t >> 6] = s; red[4 + (t >> 6)] = ss; }
    __syncthreads();
    s = red[0] + red[1] + red[2] + red[3];
    ss = red[4] + red[5] + red[6] + red[7];
    float mu = s * (1.0f / 1024.0f);
    float var = ss * (1.0f / 1024.0f) - mu * mu;
    float rstd = rsqrtf(var + 1e-5f);
    float4 g = *(const float4*)(gamma + t * 4);
    float4 be = *(const float4*)(beta + t * 4);
    float4 o;
    o.x = (v.x - mu) * rstd * g.x + be.x;
    o.y = (v.y - mu) * rstd * g.y + be.y;
    o.z = (v.z - mu) * rstd * g.z + be.z;
    o.w = (v.w - mu) * rstd * g.w + be.w;
    *(float4*)p = o;
}

extern "C" void kernel_launch(void* const* d_in, const int* in_sizes, int n_in,
                              void* d_out, int out_size, void* d_ws, size_t ws_size,
                              hipStream_t stream) {
    const float* x = (const float*)d_in[0];
    const float* Wq = (const float*)d_in[1];
    const float* bq = (const float*)d_in[2];
    const float* Wk = (const float*)d_in[3];
    const float* bk = (const float*)d_in[4];
    const float* Wv = (const float*)d_in[5];
    const float* bv = (const float*)d_in[6];
    const float* Wo = (const float*)d_in[7];
    const float* bo = (const float*)d_in[8];
    const float* gamma = (const float*)d_in[9];
    const float* beta = (const float*)d_in[10];
    float* out = (float*)d_out;

    char* ws = (char*)d_ws;
    unsigned short* x_bf = (unsigned short*)(ws);                       // 0-8 MB (reused as att)
    unsigned short* wqkv_bf = (unsigned short*)(ws + ((size_t)8 << 20));// 8-14 MB
    unsigned short* wo_bf = (unsigned short*)(ws + ((size_t)14 << 20)); // 14-16 MB
    unsigned short* qkv_ws = (unsigned short*)(ws + ((size_t)16 << 20));// 16-40 MB (q|k|vt)
    unsigned short* att = x_bf;  // alias: x_bf dead after QKV GEMM

    unsigned short* q_ws = qkv_ws;
    unsigned short* k_ws = qkv_ws + (size_t)32 * T_SEQ * DH;
    unsigned short* vt = qkv_ws + (size_t)64 * T_SEQ * DH;

    k_conv_all<<<8192, 256, 0, stream>>>(x, Wq, Wk, Wv, Wo, x_bf, wqkv_bf, wo_bf);

    // fused QKV GEMM: N = 3072, 1D grid with XCD swizzle
    k_gemm<128, 0><<<768, 256, 0, stream>>>(
        x_bf, wqkv_bf, bq, bk, bv, nullptr, qkv_ws, vt, nullptr);

    k_attn<<<512, 256, 0, stream>>>(q_ws, k_ws, vt, att);

    // O-projection + bias + residual: N = 1024, 1D grid with XCD swizzle
    k_gemm<64, 1><<<512, 256, 0, stream>>>(
        att, wo_bf, bo, nullptr, nullptr, x, nullptr, nullptr, out);

    k_ln<<<NROWS, 256, 0, stream>>>(out, gamma, beta);
}